// Round 6
// baseline (268.107 us; speedup 1.0000x reference)
//
#include <hip/hip_runtime.h>
#include <hip/hip_bf16.h>

typedef __bf16 bf16_t;
typedef __attribute__((ext_vector_type(8))) __bf16 bf16x8;
typedef __attribute__((ext_vector_type(4))) float f32x4;

#define N1 16384
#define N2 4096
#define C1 128
#define C2 256
#define CIN 384
#define HD1 256
#define HD2 128
#define BDIM 4
#define CHUNK 512
#define NCHUNK 8   // N2 / CHUNK
#define NCAND 24   // NCHUNK * 3

// ---- prep: W1/W2 -> bf16 [N][K]; f2 -> bf16 (validated R4 bodies) ----
__global__ void prep_w(const float* __restrict__ W1, const float* __restrict__ W2,
                       const float* __restrict__ f2,
                       bf16_t* __restrict__ W1t, bf16_t* __restrict__ W2t,
                       bf16_t* __restrict__ f2bf) {
  int tid = blockIdx.x * 256 + threadIdx.x;
  if (tid < CIN * HD1) {
    int k = tid / HD1, n = tid % HD1;
    W1t[n * CIN + k] = (bf16_t)W1[tid];
  }
  if (tid < HD1 * HD2) {
    int k = tid / HD2, n = tid % HD2;
    W2t[n * HD1 + k] = (bf16_t)W2[tid];
  }
  const float4* s4 = (const float4*)f2;
  float4 a = s4[2 * (size_t)tid], b = s4[2 * (size_t)tid + 1];
  bf16x8 o;
  o[0] = (bf16_t)a.x; o[1] = (bf16_t)a.y; o[2] = (bf16_t)a.z; o[3] = (bf16_t)a.w;
  o[4] = (bf16_t)b.x; o[5] = (bf16_t)b.y; o[6] = (bf16_t)b.z; o[7] = (bf16_t)b.w;
  *(bf16x8*)(f2bf + (size_t)tid * 8) = o;
}

// ---- per-chunk top-3 (VALIDATED 99.4us kernel, verbatim) ----
__global__ __launch_bounds__(256) void knn_chunk(
    const float* __restrict__ xyz1, const float* __restrict__ xyz2,
    float* __restrict__ candd, int* __restrict__ candj) {
  int b  = blockIdx.y;
  int ck = blockIdx.z;
  int i  = blockIdx.x * 256 + threadIdx.x;
  const float* p = xyz1 + ((size_t)b * N1 + i) * 3;
  float px = p[0], py = p[1], pz = p[2];

  const float* x2b = xyz2 + ((size_t)b * N2 + (size_t)ck * CHUNK) * 3;

  float d0 = 3.4e38f, d1 = 3.4e38f, d2 = 3.4e38f;
  int   j0 = 0, j1 = 0, j2 = 0;

  for (int j = 0; j < CHUNK; j += 16) {
    float c[48];
    const float4* q = (const float4*)(x2b + 3 * j);
#pragma unroll
    for (int t = 0; t < 12; ++t) {
      float4 v = q[t];
      c[4 * t + 0] = v.x; c[4 * t + 1] = v.y; c[4 * t + 2] = v.z; c[4 * t + 3] = v.w;
    }
#pragma unroll
    for (int u = 0; u < 16; ++u) {
      float dx = __fsub_rn(c[3 * u + 0], px);
      float dy = __fsub_rn(c[3 * u + 1], py);
      float dz = __fsub_rn(c[3 * u + 2], pz);
      float d = __fadd_rn(__fadd_rn(__fmul_rn(dx, dx), __fmul_rn(dy, dy)),
                          __fmul_rn(dz, dz));
      int jj = j + u;
      if (d < d2) {  // strict <: earlier index wins ties (matches top_k)
        bool lt0 = d < d0, lt1 = d < d1;
        j2 = lt1 ? j1 : jj;
        j1 = lt0 ? j0 : (lt1 ? jj : j1);
        j0 = lt0 ? jj : j0;
        d2 = __builtin_amdgcn_fmed3f(d, d1, d2);
        d1 = __builtin_amdgcn_fmed3f(d, d0, d1);
        d0 = fminf(d, d0);
      }
    }
  }
  size_t qb = ((size_t)b * N1 + i) * NCAND + (size_t)ck * 3;
  int jbase = ck * CHUNK;
  candd[qb + 0] = d0; candd[qb + 1] = d1; candd[qb + 2] = d2;
  candj[qb + 0] = j0 + jbase; candj[qb + 1] = j1 + jbase; candj[qb + 2] = j2 + jbase;
}

// ---- FUSED merge + interp + concat + GEMM1 (R4 shape, 512 threads) ----
// R5 post-mortem: 64-row tiles regressed (half MFMA/step, double W staging);
// this keeps the VALIDATED 128x256 tile and only changes wave count.
// 8 waves (2M x 4N, acc[4][4]=64 VGPR/wave) -> __launch_bounds__(512,4) =
// 2 blocks/CU = 16 waves/CU (4/SIMD), double R4's 8, to hide the f2 gather
// latency that __syncthreads' vmcnt(0) drain otherwise exposes each step.
// Merge body (validated in R5's fused_tail) runs once up front -> knn_merge
// dispatch + wq/iq round-trip eliminated. All staging patterns, fragment
// mappings, epilogue verbatim from validated kernels -> bit-identical H.
__global__ __launch_bounds__(512, 4) void interp_gemm1(
    const float* __restrict__ f1, const bf16_t* __restrict__ f2b_,
    const float* __restrict__ candd, const int* __restrict__ candj,
    const bf16_t* __restrict__ W1t, const float* __restrict__ b1,
    bf16_t* __restrict__ Hbuf) {
  __shared__ __align__(16) bf16_t As[128 * 32];      // 8 KB  [row][32k]
  __shared__ __align__(16) bf16_t Bs[4 * 256 * 8];   // 16 KB [koct][n][8k]
  __shared__ float mw[128 * 3];                      // 1.5 KB
  __shared__ int   mj[128 * 3];                      // 1.5 KB
  int tid  = threadIdx.x;
  int wv   = tid >> 6, ln = tid & 63;
  int quad = ln >> 4, lm = ln & 15;
  long row0 = (long)blockIdx.x * 128;

  // ---- merge 8x3 candidates per row (validated body) ----
  if (tid < 128) {
    size_t qq = row0 + tid;
    const float* cd = candd + qq * NCAND;
    const int*   cj = candj + qq * NCAND;
    float d0 = 3.4e38f, d1 = 3.4e38f, d2 = 3.4e38f;
    int   j0 = 0, j1 = 0, j2 = 0;
#pragma unroll
    for (int c = 0; c < NCAND; ++c) {
      float d = cd[c]; int j = cj[c];
      bool p0 = d < d0, p1 = d < d1, p2 = d < d2;
      j2 = p1 ? j1 : (p2 ? j : j2);
      j1 = p0 ? j0 : (p1 ? j : j1);
      j0 = p0 ? j : j0;
      d2 = __builtin_amdgcn_fmed3f(d, d1, d2);
      d1 = __builtin_amdgcn_fmed3f(d, d0, d1);
      d0 = fminf(d, d0);
    }
    d0 = fmaxf(d0, 1e-10f); d1 = fmaxf(d1, 1e-10f); d2 = fmaxf(d2, 1e-10f);
    float w0 = 1.0f / d0, w1 = 1.0f / d1, w2 = 1.0f / d2;
    float ws = w0 + w1 + w2;
    mw[tid * 3 + 0] = w0 / ws; mw[tid * 3 + 1] = w1 / ws; mw[tid * 3 + 2] = w2 / ws;
    mj[tid * 3 + 0] = j0; mj[tid * 3 + 1] = j1; mj[tid * 3 + 2] = j2;
  }
  __syncthreads();

  // staging role: row = tid>>2, 8 cols per thread per step
  int srow = tid >> 2, sh = tid & 3;
  long q = row0 + srow;
  int  b = (int)(q >> 14);  // N1 = 2^14
  float u0 = mw[srow * 3 + 0], u1 = mw[srow * 3 + 1], u2 = mw[srow * 3 + 2];
  const bf16_t* f2bb = f2b_ + (size_t)b * N2 * C2;
  const bf16_t* r0p = f2bb + (size_t)mj[srow * 3 + 0] * C2;
  const bf16_t* r1p = f2bb + (size_t)mj[srow * 3 + 1] * C2;
  const bf16_t* r2p = f2bb + (size_t)mj[srow * 3 + 2] * C2;
  const float* f1r = f1 + (size_t)q * C1;
  bf16_t* asd = As + srow * 32 + sh * 8;

  // mfma role: 2M x 4N waves, each 64 rows x 64 cols
  int wm = (wv >> 2) * 64, wn = (wv & 3) * 64;
  f32x4 acc[4][4] = {};

  // prefetch ks=0 gather
  bf16x8 g0, g1, g2;
  float4 gfa, gfb;
  {
    int cb = sh * 8;
    g0 = *(const bf16x8*)(r0p + cb);
    g1 = *(const bf16x8*)(r1p + cb);
    g2 = *(const bf16x8*)(r2p + cb);
  }

  for (int ks = 0; ks < 12; ++ks) {
    int kb = ks * 32;
    // W1 stage: Bs[koct][n][8], 2 issues x 512 threads x 16B = 16 KB
#pragma unroll
    for (int s = 0; s < 2; ++s) {
      int koct = s * 2 + (wv >> 2);
      int n    = (wv & 3) * 64 + ln;
      __builtin_amdgcn_global_load_lds(
          (const __attribute__((address_space(1))) void*)(
              W1t + (size_t)n * CIN + kb + koct * 8),
          (__attribute__((address_space(3))) void*)(
              Bs + koct * 2048 + (wv & 3) * 512),
          16, 0, 0);
    }
    // convert prefetched data -> A-tile slab (8 bf16 cols/thread)
    bf16x8 o;
    if (ks < 8) {
#pragma unroll
      for (int e = 0; e < 8; ++e)
        o[e] = (bf16_t)(u0 * (float)g0[e] + u1 * (float)g1[e] + u2 * (float)g2[e]);
    } else {
      o[0] = (bf16_t)gfa.x; o[1] = (bf16_t)gfa.y;
      o[2] = (bf16_t)gfa.z; o[3] = (bf16_t)gfa.w;
      o[4] = (bf16_t)gfb.x; o[5] = (bf16_t)gfb.y;
      o[6] = (bf16_t)gfb.z; o[7] = (bf16_t)gfb.w;
    }
    *(bf16x8*)(asd) = o;
    __syncthreads();

    // prefetch ks+1 (issued under MFMA phase; drained at trailing barrier)
    if (ks < 7) {
      int cb = (ks + 1) * 32 + sh * 8;
      g0 = *(const bf16x8*)(r0p + cb);
      g1 = *(const bf16x8*)(r1p + cb);
      g2 = *(const bf16x8*)(r2p + cb);
    } else if (ks < 11) {
      int cf = (ks - 7) * 32 + sh * 8;
      gfa = *(const float4*)(f1r + cf);
      gfb = *(const float4*)(f1r + cf + 4);
    }

    bf16x8 af[4];
#pragma unroll
    for (int mi = 0; mi < 4; ++mi)
      af[mi] = *(const bf16x8*)(As + (wm + mi * 16 + lm) * 32 + quad * 8);
    bf16x8 bfr[4];
#pragma unroll
    for (int ni = 0; ni < 4; ++ni)
      bfr[ni] = *(const bf16x8*)(Bs + quad * 2048 + (wn + ni * 16 + lm) * 8);
#pragma unroll
    for (int mi = 0; mi < 4; ++mi)
#pragma unroll
      for (int ni = 0; ni < 4; ++ni)
        acc[mi][ni] = __builtin_amdgcn_mfma_f32_16x16x32_bf16(af[mi], bfr[ni],
                                                              acc[mi][ni], 0, 0, 0);
    __syncthreads();
  }

  // ---- epilogue: H = relu(acc + b1) -> bf16 (validated mapping) ----
#pragma unroll
  for (int mi = 0; mi < 4; ++mi)
#pragma unroll
    for (int ni = 0; ni < 4; ++ni) {
      int col = wn + ni * 16 + lm;
      float bv = b1[col];
#pragma unroll
      for (int r = 0; r < 4; ++r) {
        long rowg = row0 + wm + mi * 16 + quad * 4 + r;
        float v = acc[mi][ni][r] + bv;
        v = fmaxf(v, 0.0f);
        Hbuf[rowg * HD1 + col] = (bf16_t)v;
      }
    }
}

// ---- bf16 MFMA GEMM (validated): C = relu(A @ Bt^T + bias) ----
template <bool OUT_BF16>
__global__ __launch_bounds__(256) void gemm_bt(
    const bf16_t* __restrict__ A, const bf16_t* __restrict__ Bt,
    const float* __restrict__ bias, void* __restrict__ Cout,
    int M, int N, int K) {
  __shared__ __align__(16) bf16_t As[128 * 32];
  __shared__ __align__(16) bf16_t Bs[128 * 32];
  int tid  = threadIdx.x;
  int wv   = tid >> 6, ln = tid & 63;
  int quad = ln >> 4, lm = ln & 15;
  long row0 = (long)blockIdx.x * 128;
  int  col0 = blockIdx.y * 128;
  const bf16_t* Ab = A + row0 * K;
  const bf16_t* Bb = Bt + (long)col0 * K;
  f32x4 acc[4][4] = {};
  int wm = (wv >> 1) * 64, wn = (wv & 1) * 64;

  for (int k0 = 0; k0 < K; k0 += 32) {
#pragma unroll
    for (int t = 0; t < 2; ++t) {
      int c = t * 256 + tid;
      int r = c >> 2, kc = (c & 3) << 3;
      __builtin_amdgcn_global_load_lds(
          (const __attribute__((address_space(1))) void*)(Ab + (long)r * K + k0 + kc),
          (__attribute__((address_space(3))) void*)(As + (t * 256 + wv * 64) * 8),
          16, 0, 0);
      __builtin_amdgcn_global_load_lds(
          (const __attribute__((address_space(1))) void*)(Bb + (long)r * K + k0 + kc),
          (__attribute__((address_space(3))) void*)(Bs + (t * 256 + wv * 64) * 8),
          16, 0, 0);
    }
    __syncthreads();
    bf16x8 af[4], bfr[4];
#pragma unroll
    for (int mi = 0; mi < 4; ++mi)
      af[mi] = *(const bf16x8*)(As + (wm + mi * 16 + lm) * 32 + quad * 8);
#pragma unroll
    for (int ni = 0; ni < 4; ++ni)
      bfr[ni] = *(const bf16x8*)(Bs + (wn + ni * 16 + lm) * 32 + quad * 8);
#pragma unroll
    for (int mi = 0; mi < 4; ++mi)
#pragma unroll
      for (int ni = 0; ni < 4; ++ni)
        acc[mi][ni] = __builtin_amdgcn_mfma_f32_16x16x32_bf16(af[mi], bfr[ni],
                                                              acc[mi][ni], 0, 0, 0);
    __syncthreads();
  }

#pragma unroll
  for (int mi = 0; mi < 4; ++mi)
#pragma unroll
    for (int ni = 0; ni < 4; ++ni) {
      int col = col0 + wn + ni * 16 + lm;
      float bv = bias[col];
#pragma unroll
      for (int r = 0; r < 4; ++r) {
        long rowg = row0 + wm + mi * 16 + quad * 4 + r;
        float v = acc[mi][ni][r] + bv;
        v = fmaxf(v, 0.0f);
        if (OUT_BF16) ((bf16_t*)Cout)[rowg * N + col] = (bf16_t)v;
        else          ((float*)Cout)[rowg * N + col]  = v;
      }
    }
}

extern "C" void kernel_launch(void* const* d_in, const int* in_sizes, int n_in,
                              void* d_out, int out_size, void* d_ws, size_t ws_size,
                              hipStream_t stream) {
  const float* xyz1 = (const float*)d_in[0];
  const float* xyz2 = (const float*)d_in[1];
  const float* f1   = (const float*)d_in[2];
  const float* f2   = (const float*)d_in[3];
  const float* W1   = (const float*)d_in[4];
  const float* b1   = (const float*)d_in[5];
  const float* W2   = (const float*)d_in[6];
  const float* b2   = (const float*)d_in[7];
  float* out = (float*)d_out;

  const size_t NQ = (size_t)BDIM * N1;  // 65536
  char* ws = (char*)d_ws;
  bf16_t* W1t  = (bf16_t*)ws;                        // 192 KB
  bf16_t* W2t  = (bf16_t*)(ws + (256 << 10));        // 64 KB
  bf16_t* f2bf = (bf16_t*)(ws + (512 << 10));        // 8.4 MB
  float*  candd = (float*)(ws + (10 << 20));         // 12.6 MB
  int*    candj = (int*)(ws + (23 << 20));           // 12.6 MB
  bf16_t* Hbuf  = (bf16_t*)(ws + (36 << 20));        // 33.5 MB

  prep_w<<<dim3(2048), dim3(256), 0, stream>>>(W1, W2, f2, W1t, W2t, f2bf);
  knn_chunk<<<dim3(N1 / 256, BDIM, NCHUNK), dim3(256), 0, stream>>>(
      xyz1, xyz2, candd, candj);
  interp_gemm1<<<dim3(NQ / 128), dim3(512), 0, stream>>>(
      f1, f2bf, candd, candj, W1t, b1, Hbuf);
  gemm_bt<false><<<dim3(NQ / 128, HD2 / 128), dim3(256), 0, stream>>>(
      Hbuf, W2t, b2, (void*)out, NQ, HD2, HD1);
}

// Round 7
// 245.205 us; speedup vs baseline: 1.0934x; 1.0934x over previous
//
#include <hip/hip_runtime.h>
#include <hip/hip_bf16.h>

typedef __bf16 bf16_t;
typedef __attribute__((ext_vector_type(8))) __bf16 bf16x8;
typedef __attribute__((ext_vector_type(4))) __bf16 bf16x4;
typedef __attribute__((ext_vector_type(4))) float f32x4;

#define N1 16384
#define N2 4096
#define C1 128
#define C2 256
#define CIN 384
#define HD1 256
#define HD2 128
#define BDIM 4
#define CHUNK 512
#define NCHUNK 8   // N2 / CHUNK
#define NCAND 24   // NCHUNK * 3

// ---- prep: weights -> bf16 [N][K]; f2 -> bf16 (halves scattered gather bytes,
// shrinks slab 16.8->8.4 MB so per-XCD L2 hit rate ~doubles) ----
__global__ void prep_w(const float* __restrict__ W1, const float* __restrict__ W2,
                       const float* __restrict__ f2,
                       bf16_t* __restrict__ W1t, bf16_t* __restrict__ W2t,
                       bf16_t* __restrict__ f2bf) {
  int tid = blockIdx.x * 256 + threadIdx.x;
  if (tid < CIN * HD1) {
    int k = tid / HD1, n = tid % HD1;
    W1t[n * CIN + k] = (bf16_t)W1[tid];
  }
  if (tid < HD1 * HD2) {
    int k = tid / HD2, n = tid % HD2;
    W2t[n * HD1 + k] = (bf16_t)W2[tid];
  }
  // f2 cast: 8 floats per thread (BDIM*N2*C2 = 4.19M elements, grid 2048x256)
  const float4* s4 = (const float4*)f2;
  float4 a = s4[2 * (size_t)tid], b = s4[2 * (size_t)tid + 1];
  bf16x8 o;
  o[0] = (bf16_t)a.x; o[1] = (bf16_t)a.y; o[2] = (bf16_t)a.z; o[3] = (bf16_t)a.w;
  o[4] = (bf16_t)b.x; o[5] = (bf16_t)b.y; o[6] = (bf16_t)b.z; o[7] = (bf16_t)b.w;
  *(bf16x8*)(f2bf + (size_t)tid * 8) = o;
}

// ---- per-chunk top-3 (VALIDATED 99.4us kernel, verbatim) ----
__global__ __launch_bounds__(256) void knn_chunk(
    const float* __restrict__ xyz1, const float* __restrict__ xyz2,
    float* __restrict__ candd, int* __restrict__ candj) {
  int b  = blockIdx.y;
  int ck = blockIdx.z;
  int i  = blockIdx.x * 256 + threadIdx.x;
  const float* p = xyz1 + ((size_t)b * N1 + i) * 3;
  float px = p[0], py = p[1], pz = p[2];

  const float* x2b = xyz2 + ((size_t)b * N2 + (size_t)ck * CHUNK) * 3;

  float d0 = 3.4e38f, d1 = 3.4e38f, d2 = 3.4e38f;
  int   j0 = 0, j1 = 0, j2 = 0;

  for (int j = 0; j < CHUNK; j += 16) {
    float c[48];
    const float4* q = (const float4*)(x2b + 3 * j);
#pragma unroll
    for (int t = 0; t < 12; ++t) {
      float4 v = q[t];
      c[4 * t + 0] = v.x; c[4 * t + 1] = v.y; c[4 * t + 2] = v.z; c[4 * t + 3] = v.w;
    }
#pragma unroll
    for (int u = 0; u < 16; ++u) {
      float dx = __fsub_rn(c[3 * u + 0], px);
      float dy = __fsub_rn(c[3 * u + 1], py);
      float dz = __fsub_rn(c[3 * u + 2], pz);
      float d = __fadd_rn(__fadd_rn(__fmul_rn(dx, dx), __fmul_rn(dy, dy)),
                          __fmul_rn(dz, dz));
      int jj = j + u;
      if (d < d2) {  // strict <: earlier index wins ties (matches top_k)
        bool lt0 = d < d0, lt1 = d < d1;
        j2 = lt1 ? j1 : jj;
        j1 = lt0 ? j0 : (lt1 ? jj : j1);
        j0 = lt0 ? jj : j0;
        d2 = __builtin_amdgcn_fmed3f(d, d1, d2);
        d1 = __builtin_amdgcn_fmed3f(d, d0, d1);
        d0 = fminf(d, d0);
      }
    }
  }
  size_t qb = ((size_t)b * N1 + i) * NCAND + (size_t)ck * 3;
  int jbase = ck * CHUNK;
  candd[qb + 0] = d0; candd[qb + 1] = d1; candd[qb + 2] = d2;
  candj[qb + 0] = j0 + jbase; candj[qb + 1] = j1 + jbase; candj[qb + 2] = j2 + jbase;
}

// ---- merge 8x3 candidates -> final top-3 + normalized weights ----
__global__ __launch_bounds__(256) void knn_merge(
    const float* __restrict__ candd, const int* __restrict__ candj,
    float* __restrict__ wq, int* __restrict__ iq) {
  int q = blockIdx.x * 256 + threadIdx.x;
  const float* cd = candd + (size_t)q * NCAND;
  const int*   cj = candj + (size_t)q * NCAND;
  float d0 = 3.4e38f, d1 = 3.4e38f, d2 = 3.4e38f;
  int   j0 = 0, j1 = 0, j2 = 0;
#pragma unroll
  for (int c = 0; c < NCAND; ++c) {
    float d = cd[c]; int j = cj[c];
    bool p0 = d < d0, p1 = d < d1, p2 = d < d2;
    j2 = p1 ? j1 : (p2 ? j : j2);
    j1 = p0 ? j0 : (p1 ? j : j1);
    j0 = p0 ? j : j0;
    d2 = __builtin_amdgcn_fmed3f(d, d1, d2);
    d1 = __builtin_amdgcn_fmed3f(d, d0, d1);
    d0 = fminf(d, d0);
  }
  d0 = fmaxf(d0, 1e-10f); d1 = fmaxf(d1, 1e-10f); d2 = fmaxf(d2, 1e-10f);
  float w0 = 1.0f / d0, w1 = 1.0f / d1, w2 = 1.0f / d2;
  float ws = w0 + w1 + w2;
  wq[q * 3 + 0] = w0 / ws; wq[q * 3 + 1] = w1 / ws; wq[q * 3 + 2] = w2 / ws;
  iq[q * 3 + 0] = j0; iq[q * 3 + 1] = j1; iq[q * 3 + 2] = j2;
}

// ---- FUSED interp+concat+GEMM1 with pipelined bf16 gather (R4, verbatim) ----
__global__ __launch_bounds__(256, 2) void interp_gemm1(
    const float* __restrict__ f1, const bf16_t* __restrict__ f2b_,
    const float* __restrict__ wq, const int* __restrict__ iq,
    const bf16_t* __restrict__ W1t, const float* __restrict__ b1,
    bf16_t* __restrict__ Hbuf) {
  __shared__ __align__(16) bf16_t As[128 * 32];      // 8 KB  [row][32k]
  __shared__ __align__(16) bf16_t Bs[4 * 256 * 8];   // 16 KB [quad][n][8k]
  int tid  = threadIdx.x;
  int wv   = tid >> 6, ln = tid & 63;
  int quad = ln >> 4, lm = ln & 15;
  long row0 = (long)blockIdx.x * 128;

  int srow = tid >> 1;
  int sh   = tid & 1;
  long q = row0 + srow;
  int  b = (int)(q >> 14);  // N1 = 2^14
  float u0 = wq[q * 3 + 0], u1 = wq[q * 3 + 1], u2 = wq[q * 3 + 2];
  const bf16_t* f2bb = f2b_ + (size_t)b * N2 * C2;
  const bf16_t* r0 = f2bb + (size_t)iq[q * 3 + 0] * C2;
  const bf16_t* r1 = f2bb + (size_t)iq[q * 3 + 1] * C2;
  const bf16_t* r2 = f2bb + (size_t)iq[q * 3 + 2] * C2;
  const float* f1r = f1 + (size_t)q * C1;
  bf16_t* asd = As + srow * 32 + sh * 16;

  int wm = (wv >> 1) * 64, wn = (wv & 1) * 128;
  f32x4 acc[4][8] = {};

  // prefetch registers
  bf16x8 g0a, g0b, g1a, g1b, g2a, g2b;  // f2 path (ks<8): 16 cols x 3 nbrs
  float4 gf[4];                          // f1 path (ks>=8): 16 cols fp32
  {
    int cb = sh * 16;
    g0a = *(const bf16x8*)(r0 + cb); g0b = *(const bf16x8*)(r0 + cb + 8);
    g1a = *(const bf16x8*)(r1 + cb); g1b = *(const bf16x8*)(r1 + cb + 8);
    g2a = *(const bf16x8*)(r2 + cb); g2b = *(const bf16x8*)(r2 + cb + 8);
  }

  for (int ks = 0; ks < 12; ++ks) {
    int kb = ks * 32;
    // W1 stage (DMA; dest Bs free since previous step's trailing barrier)
#pragma unroll
    for (int s = 0; s < 4; ++s) {
      __builtin_amdgcn_global_load_lds(
          (const __attribute__((address_space(1))) void*)(
              W1t + (size_t)(wv * 64 + ln) * CIN + kb + s * 8),
          (__attribute__((address_space(3))) void*)(Bs + s * 2048 + wv * 512),
          16, 0, 0);
    }
    // convert prefetched data -> A-tile slab (16 bf16 cols)
    bf16x8 o[2];
    if (ks < 8) {
#pragma unroll
      for (int e = 0; e < 8; ++e) {
        o[0][e] = (bf16_t)(u0 * (float)g0a[e] + u1 * (float)g1a[e] +
                           u2 * (float)g2a[e]);
        o[1][e] = (bf16_t)(u0 * (float)g0b[e] + u1 * (float)g1b[e] +
                           u2 * (float)g2b[e]);
      }
    } else {
#pragma unroll
      for (int c4 = 0; c4 < 4; ++c4) {
        float4 g = gf[c4];
        int oi = c4 >> 1, off = (c4 & 1) * 4;
        o[oi][off + 0] = (bf16_t)g.x;
        o[oi][off + 1] = (bf16_t)g.y;
        o[oi][off + 2] = (bf16_t)g.z;
        o[oi][off + 3] = (bf16_t)g.w;
      }
    }
    *(bf16x8*)(asd) = o[0];
    *(bf16x8*)(asd + 8) = o[1];
    __syncthreads();

    // prefetch step ks+1 (in flight across the MFMA phase; drained by the
    // compiler's vmcnt(0) before the trailing barrier)
    if (ks < 7) {
      int cb = (ks + 1) * 32 + sh * 16;
      g0a = *(const bf16x8*)(r0 + cb); g0b = *(const bf16x8*)(r0 + cb + 8);
      g1a = *(const bf16x8*)(r1 + cb); g1b = *(const bf16x8*)(r1 + cb + 8);
      g2a = *(const bf16x8*)(r2 + cb); g2b = *(const bf16x8*)(r2 + cb + 8);
    } else if (ks < 11) {
      int cf = (ks - 7) * 32 + sh * 16;
#pragma unroll
      for (int c4 = 0; c4 < 4; ++c4)
        gf[c4] = *(const float4*)(f1r + cf + c4 * 4);
    }

    bf16x8 af[4];
#pragma unroll
    for (int mi = 0; mi < 4; ++mi)
      af[mi] = *(const bf16x8*)(As + (wm + mi * 16 + lm) * 32 + quad * 8);
#pragma unroll
    for (int nh = 0; nh < 2; ++nh) {
      bf16x8 bfr[4];
#pragma unroll
      for (int nn = 0; nn < 4; ++nn)
        bfr[nn] = *(const bf16x8*)(Bs + quad * 2048 + (wn + (nh * 4 + nn) * 16 + lm) * 8);
#pragma unroll
      for (int mi = 0; mi < 4; ++mi)
#pragma unroll
        for (int nn = 0; nn < 4; ++nn)
          acc[mi][nh * 4 + nn] = __builtin_amdgcn_mfma_f32_16x16x32_bf16(
              af[mi], bfr[nn], acc[mi][nh * 4 + nn], 0, 0, 0);
    }
    __syncthreads();
  }

#pragma unroll
  for (int mi = 0; mi < 4; ++mi)
#pragma unroll
    for (int ni = 0; ni < 8; ++ni) {
      int col = wn + ni * 16 + lm;
      float bv = b1[col];
#pragma unroll
      for (int r = 0; r < 4; ++r) {
        long rowg = row0 + wm + mi * 16 + quad * 4 + r;
        float v = acc[mi][ni][r] + bv;
        v = fmaxf(v, 0.0f);
        Hbuf[rowg * HD1 + col] = (bf16_t)v;
      }
    }
}

// ---- bf16 MFMA GEMM (validated): C = relu(A @ Bt^T + bias) ----
template <bool OUT_BF16>
__global__ __launch_bounds__(256) void gemm_bt(
    const bf16_t* __restrict__ A, const bf16_t* __restrict__ Bt,
    const float* __restrict__ bias, void* __restrict__ Cout,
    int M, int N, int K) {
  __shared__ __align__(16) bf16_t As[128 * 32];
  __shared__ __align__(16) bf16_t Bs[128 * 32];
  int tid  = threadIdx.x;
  int wv   = tid >> 6, ln = tid & 63;
  int quad = ln >> 4, lm = ln & 15;
  long row0 = (long)blockIdx.x * 128;
  int  col0 = blockIdx.y * 128;
  const bf16_t* Ab = A + row0 * K;
  const bf16_t* Bb = Bt + (long)col0 * K;
  f32x4 acc[4][4] = {};
  int wm = (wv >> 1) * 64, wn = (wv & 1) * 64;

  for (int k0 = 0; k0 < K; k0 += 32) {
#pragma unroll
    for (int t = 0; t < 2; ++t) {
      int c = t * 256 + tid;
      int r = c >> 2, kc = (c & 3) << 3;
      __builtin_amdgcn_global_load_lds(
          (const __attribute__((address_space(1))) void*)(Ab + (long)r * K + k0 + kc),
          (__attribute__((address_space(3))) void*)(As + (t * 256 + wv * 64) * 8),
          16, 0, 0);
      __builtin_amdgcn_global_load_lds(
          (const __attribute__((address_space(1))) void*)(Bb + (long)r * K + k0 + kc),
          (__attribute__((address_space(3))) void*)(Bs + (t * 256 + wv * 64) * 8),
          16, 0, 0);
    }
    __syncthreads();
    bf16x8 af[4], bfr[4];
#pragma unroll
    for (int mi = 0; mi < 4; ++mi)
      af[mi] = *(const bf16x8*)(As + (wm + mi * 16 + lm) * 32 + quad * 8);
#pragma unroll
    for (int ni = 0; ni < 4; ++ni)
      bfr[ni] = *(const bf16x8*)(Bs + (wn + ni * 16 + lm) * 32 + quad * 8);
#pragma unroll
    for (int mi = 0; mi < 4; ++mi)
#pragma unroll
      for (int ni = 0; ni < 4; ++ni)
        acc[mi][ni] = __builtin_amdgcn_mfma_f32_16x16x32_bf16(af[mi], bfr[ni],
                                                              acc[mi][ni], 0, 0, 0);
    __syncthreads();
  }

#pragma unroll
  for (int mi = 0; mi < 4; ++mi)
#pragma unroll
    for (int ni = 0; ni < 4; ++ni) {
      int col = col0 + wn + ni * 16 + lm;
      float bv = bias[col];
#pragma unroll
      for (int r = 0; r < 4; ++r) {
        long rowg = row0 + wm + mi * 16 + quad * 4 + r;
        float v = acc[mi][ni][r] + bv;
        v = fmaxf(v, 0.0f);
        if (OUT_BF16) ((bf16_t*)Cout)[rowg * N + col] = (bf16_t)v;
        else          ((float*)Cout)[rowg * N + col]  = v;
      }
    }
}

extern "C" void kernel_launch(void* const* d_in, const int* in_sizes, int n_in,
                              void* d_out, int out_size, void* d_ws, size_t ws_size,
                              hipStream_t stream) {
  const float* xyz1 = (const float*)d_in[0];
  const float* xyz2 = (const float*)d_in[1];
  const float* f1   = (const float*)d_in[2];
  const float* f2   = (const float*)d_in[3];
  const float* W1   = (const float*)d_in[4];
  const float* b1   = (const float*)d_in[5];
  const float* W2   = (const float*)d_in[6];
  const float* b2   = (const float*)d_in[7];
  float* out = (float*)d_out;

  const size_t NQ = (size_t)BDIM * N1;  // 65536
  char* ws = (char*)d_ws;
  bf16_t* W1t = (bf16_t*)ws;                         // 192 KB
  bf16_t* W2t = (bf16_t*)(ws + (256 << 10));         // 64 KB
  float*  wq  = (float*)(ws + (512 << 10));          // 768 KB
  int*    iq  = (int*)(ws + (1536 << 10));           // 768 KB
  bf16_t* f2bf = (bf16_t*)(ws + (2560 << 10));       // 8.4 MB (in old NF gap)
  char*   hb  = ws + (2560 << 10) + NQ * CIN * 2;
  bf16_t* Hbuf  = (bf16_t*)hb;
  // candidates alias Hbuf (consumed by merge before interp_gemm1 writes Hbuf)
  float*  candd = (float*)hb;                        // 6.3 MB
  int*    candj = (int*)(hb + NQ * NCAND * 4);       // 6.3 MB

  prep_w<<<dim3(2048), dim3(256), 0, stream>>>(W1, W2, f2, W1t, W2t, f2bf);
  knn_chunk<<<dim3(N1 / 256, BDIM, NCHUNK), dim3(256), 0, stream>>>(
      xyz1, xyz2, candd, candj);
  knn_merge<<<dim3(NQ / 256), dim3(256), 0, stream>>>(candd, candj, wq, iq);
  interp_gemm1<<<dim3(NQ / 128), dim3(256), 0, stream>>>(
      f1, f2bf, wq, iq, W1t, b1, Hbuf);
  gemm_bt<false><<<dim3(NQ / 128, HD2 / 128), dim3(256), 0, stream>>>(
      Hbuf, W2t, b2, (void*)out, NQ, HD2, HD1);
}